// Round 2
// baseline (574.110 us; speedup 1.0000x reference)
//
#include <hip/hip_runtime.h>
#include <hip/hip_bf16.h>
#include <cstdint>
#include <math.h>

typedef int v4i __attribute__((ext_vector_type(4)));

// ---------------- float atomic min/max via int tricks ----------------
__device__ __forceinline__ void atomicMinF(float* addr, float v) {
  if (v >= 0.f) atomicMin((int*)addr, __float_as_int(v));
  else          atomicMax((unsigned int*)addr, __float_as_uint(v));
}
__device__ __forceinline__ void atomicMaxF(float* addr, float v) {
  if (v >= 0.f) atomicMax((int*)addr, __float_as_int(v));
  else          atomicMin((unsigned int*)addr, __float_as_uint(v));
}

// ---------------- init params block (ws poisoned 0xAA every call) ----------------
__global__ void init_params_kernel(float* p) {
  p[0] =  INFINITY;  // xmin
  p[1] = -INFINITY;  // xmax
  p[2] =  INFINITY;  // wmin
  p[3] = -INFINITY;  // wmax
}

// ---------------- global min/max: 4 independent chains, 64B/lane ----------------
__global__ __launch_bounds__(256) void minmax_kernel(const float* __restrict__ a, long long n,
                                                     float* mnp, float* mxp) {
  const float4* a4 = (const float4*)a;
  const long long n4 = n >> 2;
  const long long tid = (long long)blockIdx.x * blockDim.x + threadIdx.x;
  const long long stride = (long long)gridDim.x * blockDim.x * 4;
  float mn0 = INFINITY, mx0 = -INFINITY, mn1 = INFINITY, mx1 = -INFINITY;
  float mn2 = INFINITY, mx2 = -INFINITY, mn3 = INFINITY, mx3 = -INFINITY;
  if (blockIdx.x == 0 && threadIdx.x < (int)(n & 3)) {
    float v = a[n4 * 4 + threadIdx.x];
    mn0 = fminf(mn0, v); mx0 = fmaxf(mx0, v);
  }
  long long i = tid * 4;
  for (; i + 4 <= n4; i += stride) {
    float4 v0 = a4[i], v1 = a4[i + 1], v2 = a4[i + 2], v3 = a4[i + 3];
    mn0 = fminf(mn0, fminf(fminf(v0.x, v0.y), fminf(v0.z, v0.w)));
    mx0 = fmaxf(mx0, fmaxf(fmaxf(v0.x, v0.y), fmaxf(v0.z, v0.w)));
    mn1 = fminf(mn1, fminf(fminf(v1.x, v1.y), fminf(v1.z, v1.w)));
    mx1 = fmaxf(mx1, fmaxf(fmaxf(v1.x, v1.y), fmaxf(v1.z, v1.w)));
    mn2 = fminf(mn2, fminf(fminf(v2.x, v2.y), fminf(v2.z, v2.w)));
    mx2 = fmaxf(mx2, fmaxf(fmaxf(v2.x, v2.y), fmaxf(v2.z, v2.w)));
    mn3 = fminf(mn3, fminf(fminf(v3.x, v3.y), fminf(v3.z, v3.w)));
    mx3 = fmaxf(mx3, fmaxf(fmaxf(v3.x, v3.y), fmaxf(v3.z, v3.w)));
  }
  for (; i < n4; ++i) {
    float4 v = a4[i];
    mn0 = fminf(mn0, fminf(fminf(v.x, v.y), fminf(v.z, v.w)));
    mx0 = fmaxf(mx0, fmaxf(fmaxf(v.x, v.y), fmaxf(v.z, v.w)));
  }
  float mn = fminf(fminf(mn0, mn1), fminf(mn2, mn3));
  float mx = fmaxf(fmaxf(mx0, mx1), fmaxf(mx2, mx3));
  #pragma unroll
  for (int off = 32; off; off >>= 1) {
    mn = fminf(mn, __shfl_xor(mn, off));
    mx = fmaxf(mx, __shfl_xor(mx, off));
  }
  __shared__ float smn[4], smx[4];
  int wv = threadIdx.x >> 6;
  if ((threadIdx.x & 63) == 0) { smn[wv] = mn; smx[wv] = mx; }
  __syncthreads();
  if (threadIdx.x == 0) {
    mn = fminf(fminf(smn[0], smn[1]), fminf(smn[2], smn[3]));
    mx = fmaxf(fmaxf(smx[0], smx[1]), fmaxf(smx[2], smx[3]));
    atomicMinF(mnp, mn);
    atomicMaxF(mxp, mx);
  }
}

// ---------------- scalar quant params (mirrors reference exactly) ----------------
__global__ void compute_params_kernel(float* p, const int* bits, float Kf) {
  float n   = (float)((1u << bits[0]) - 1u);
  float xmn = p[0], xmx = p[1], wmn = p[2], wmx = p[3];
  float S1 = (wmx - wmn) / n;
  float Z1 = rintf(n * wmn / (wmn - wmx));
  float S2 = (xmx - xmn) / n;
  float Z2 = rintf(n * xmn / (xmn - xmx));
  float s1s2 = S1 * S2;
  p[4]  = s1s2;
  p[5]  = 128.0f - Z2;                    // multiplies rowsum(q1)[o]
  p[6]  = 128.0f - Z1;                    // multiplies rowsum(xq)[i]
  p[7]  = (Z1 * Z2 - 16384.0f) * Kf;      // constant term
  p[8]  = S2;
  p[9]  = Z2;
  p[10] = wmn;
  p[11] = wmx - wmn;
  p[12] = n;
}

__device__ __forceinline__ unsigned qpack_w(float4 v, float wmn, float wrng, float n, int& sum) {
  int q0 = (int)rintf((v.x - wmn) / wrng * n);
  int q1 = (int)rintf((v.y - wmn) / wrng * n);
  int q2 = (int)rintf((v.z - wmn) / wrng * n);
  int q3 = (int)rintf((v.w - wmn) / wrng * n);
  sum += q0 + q1 + q2 + q3;
  return ((unsigned)((q0 - 128) & 255)) | ((unsigned)((q1 - 128) & 255) << 8)
       | ((unsigned)((q2 - 128) & 255) << 16) | ((unsigned)((q3 - 128) & 255) << 24);
}
__device__ __forceinline__ unsigned qpack_x(float4 v, float S2, float Z2, float n, int& sum) {
  int q0 = (int)fminf(fmaxf(rintf(v.x / S2 + Z2), 0.f), n);
  int q1 = (int)fminf(fmaxf(rintf(v.y / S2 + Z2), 0.f), n);
  int q2 = (int)fminf(fmaxf(rintf(v.z / S2 + Z2), 0.f), n);
  int q3 = (int)fminf(fmaxf(rintf(v.w / S2 + Z2), 0.f), n);
  sum += q0 + q1 + q2 + q3;
  return ((unsigned)((q0 - 128) & 255)) | ((unsigned)((q1 - 128) & 255) << 8)
       | ((unsigned)((q2 - 128) & 255) << 16) | ((unsigned)((q3 - 128) & 255) << 24);
}

// ---------------- quantize W row -> int8 (shifted -128), rowsum, col constant ----------------
__global__ __launch_bounds__(256) void quant_w_kernel(const float* __restrict__ W,
                                                      const float* __restrict__ bias,
                                                      const float* __restrict__ p,
                                                      int8_t* __restrict__ q1,
                                                      float* __restrict__ colC, int K) {
  const int o = blockIdx.x;
  const float wmn = p[10], wrng = p[11], n = p[12], s1s2 = p[4], cW = p[5], cC = p[7];
  const float4* Wr = (const float4*)(W + (size_t)o * K);
  unsigned int* qr = (unsigned int*)(q1 + (size_t)o * K);
  int sum = 0;
  const int K4 = K >> 2;
  int c = threadIdx.x;
  for (; c + 768 < K4; c += 1024) {
    float4 v0 = Wr[c], v1 = Wr[c + 256], v2 = Wr[c + 512], v3 = Wr[c + 768];
    qr[c]       = qpack_w(v0, wmn, wrng, n, sum);
    qr[c + 256] = qpack_w(v1, wmn, wrng, n, sum);
    qr[c + 512] = qpack_w(v2, wmn, wrng, n, sum);
    qr[c + 768] = qpack_w(v3, wmn, wrng, n, sum);
  }
  for (; c < K4; c += 256) qr[c] = qpack_w(Wr[c], wmn, wrng, n, sum);
  #pragma unroll
  for (int off = 32; off; off >>= 1) sum += __shfl_xor(sum, off);
  __shared__ int ps[4];
  if ((threadIdx.x & 63) == 0) ps[threadIdx.x >> 6] = sum;
  __syncthreads();
  if (threadIdx.x == 0) {
    float tot = (float)(ps[0] + ps[1] + ps[2] + ps[3]);
    colC[o] = cW * tot + rintf(bias[o] / s1s2) + cC;
  }
}

// ---------------- quantize x row -> int8 (shifted -128), rowsum, row constant ----------------
__global__ __launch_bounds__(256) void quant_x_kernel(const float* __restrict__ x,
                                                      const float* __restrict__ p,
                                                      int8_t* __restrict__ xq,
                                                      float* __restrict__ rowC, int K) {
  const int i = blockIdx.x;
  const float S2 = p[8], Z2 = p[9], n = p[12], cX = p[6];
  const float4* xr = (const float4*)(x + (size_t)i * K);
  unsigned int* qr = (unsigned int*)(xq + (size_t)i * K);
  int sum = 0;
  const int K4 = K >> 2;
  int c = threadIdx.x;
  for (; c + 768 < K4; c += 1024) {
    float4 v0 = xr[c], v1 = xr[c + 256], v2 = xr[c + 512], v3 = xr[c + 768];
    qr[c]       = qpack_x(v0, S2, Z2, n, sum);
    qr[c + 256] = qpack_x(v1, S2, Z2, n, sum);
    qr[c + 512] = qpack_x(v2, S2, Z2, n, sum);
    qr[c + 768] = qpack_x(v3, S2, Z2, n, sum);
  }
  for (; c < K4; c += 256) qr[c] = qpack_x(xr[c], S2, Z2, n, sum);
  #pragma unroll
  for (int off = 32; off; off >>= 1) sum += __shfl_xor(sum, off);
  __shared__ int ps[4];
  if ((threadIdx.x & 63) == 0) ps[threadIdx.x >> 6] = sum;
  __syncthreads();
  if (threadIdx.x == 0) {
    float tot = (float)(ps[0] + ps[1] + ps[2] + ps[3]);
    rowC[i] = cX * tot;
  }
}

// ---------------- async global->LDS 16B helper ----------------
__device__ __forceinline__ void gload_lds16(const void* g, void* l) {
  __builtin_amdgcn_global_load_lds((const __attribute__((address_space(1))) void*)g,
                                   (__attribute__((address_space(3))) void*)l, 16, 0, 0);
}

// ---------------- int8 MFMA GEMM, 2-phase double-buffered ----------------
// BM=BN=128, BK=64 bytes, 256 thr = 4 waves (2x2), wave = 64x64 out = 4x4 frags 16x16x64.
// LDS: 2 x (8KB A + 8KB B) = 32KB -> 4-5 blocks/CU.
// Swizzle: LDS[row][s] holds global seg s ^ ((row>>2)&3)  (conflict-free b128 reads).
__global__ __launch_bounds__(256) void gemm_i8_kernel(const int8_t* __restrict__ xq,
                                                      const int8_t* __restrict__ q1,
                                                      const float* __restrict__ p,
                                                      const float* __restrict__ colC,
                                                      const float* __restrict__ rowC,
                                                      float* __restrict__ out,
                                                      int M, int N, int K) {
  __shared__ int8_t As[2][128 * 64];
  __shared__ int8_t Bs[2][128 * 64];

  const int tid  = threadIdx.x;
  const int lane = tid & 63;
  const int wv   = tid >> 6;
  const int wr   = wv >> 1;
  const int wc   = wv & 1;
  const int r15  = lane & 15;
  const int kg   = lane >> 4;

  // bijective XCD swizzle: same-XCD blocks get contiguous tiles (share A panels in L2)
  const int nwg = gridDim.x;
  const int nbn = N >> 7;
  int tl;
  if ((nwg & 7) == 0) {
    tl = (blockIdx.x & 7) * (nwg >> 3) + (blockIdx.x >> 3);
  } else {
    tl = blockIdx.x;
  }
  const int bm = tl / nbn;
  const int bn = tl % nbn;

  v4i acc[4][4];
  #pragma unroll
  for (int m = 0; m < 4; ++m)
    #pragma unroll
    for (int n = 0; n < 4; ++n) { v4i z = {0, 0, 0, 0}; acc[m][n] = z; }

  const size_t Abase = (size_t)bm * 128 * K;
  const size_t Bbase = (size_t)bn * 128 * K;
  const int srow = tid >> 2;          // 0..63 per issue
  const int sseg = tid & 3;
  const int sg   = sseg ^ ((srow >> 2) & 3);      // source seg (involution)
  const int swoff = ((kg ^ ((r15 >> 2) & 3)) << 4);  // read-side swizzled byte offset

  const int NT = K >> 6;

  // prologue: stage tile 0 into buf 0
  #pragma unroll
  for (int i = 0; i < 2; ++i) {
    const size_t roff = (size_t)(i * 64 + srow) * K + sg * 16;
    gload_lds16(xq + Abase + roff, &As[0][i * 4096 + tid * 16]);
    gload_lds16(q1 + Bbase + roff, &Bs[0][i * 4096 + tid * 16]);
  }
  __syncthreads();

  for (int kt = 0; kt < NT; ++kt) {
    const int cur = kt & 1;
    if (kt + 1 < NT) {  // stage next tile into other buffer (loads fly under compute)
      const int kof = (kt + 1) << 6;
      #pragma unroll
      for (int i = 0; i < 2; ++i) {
        const size_t roff = (size_t)(i * 64 + srow) * K + kof + sg * 16;
        gload_lds16(xq + Abase + roff, &As[cur ^ 1][i * 4096 + tid * 16]);
        gload_lds16(q1 + Bbase + roff, &Bs[cur ^ 1][i * 4096 + tid * 16]);
      }
    }
    const int8_t* as = As[cur];
    const int8_t* bs = Bs[cur];
    v4i af[4], bf[4];
    #pragma unroll
    for (int m = 0; m < 4; ++m)
      af[m] = *(const v4i*)&as[(wr * 64 + m * 16 + r15) * 64 + swoff];
    #pragma unroll
    for (int n = 0; n < 4; ++n)
      bf[n] = *(const v4i*)&bs[(wc * 64 + n * 16 + r15) * 64 + swoff];
    #pragma unroll
    for (int m = 0; m < 4; ++m)
      #pragma unroll
      for (int n = 0; n < 4; ++n)
        acc[m][n] = __builtin_amdgcn_mfma_i32_16x16x64_i8(af[m], bf[n], acc[m][n], 0, 0, 0);
    __syncthreads();  // drains vmcnt(0) (next tile arrived) + lgkmcnt (reads done)
  }

  // epilogue: out[i,o] = s1s2 * (dot + colC[o] + rowC[i])
  const float s1s2 = p[4];
  const int orow0 = bm * 128 + wr * 64;
  const int ocol0 = bn * 128 + wc * 64;
  #pragma unroll
  for (int n = 0; n < 4; ++n) {
    const int go = ocol0 + n * 16 + r15;
    const float cc = colC[go];
    #pragma unroll
    for (int m = 0; m < 4; ++m) {
      const int gibase = orow0 + m * 16 + kg * 4;
      #pragma unroll
      for (int r = 0; r < 4; ++r) {
        const int gi = gibase + r;
        out[(size_t)gi * N + go] = s1s2 * ((float)acc[m][n][r] + cc + rowC[gi]);
      }
    }
  }
}

// ---------------- host launch ----------------
extern "C" void kernel_launch(void* const* d_in, const int* in_sizes, int n_in,
                              void* d_out, int out_size, void* d_ws, size_t ws_size,
                              hipStream_t stream) {
  const float* x    = (const float*)d_in[0];
  const float* W    = (const float*)d_in[1];
  const float* b    = (const float*)d_in[2];
  const int*   bits = (const int*)d_in[3];

  const long long xN = in_sizes[0];
  const long long wN = in_sizes[1];
  const int O = in_sizes[2];
  const int K = (int)(wN / O);
  const int M = (int)(xN / K);

  char* ws = (char*)d_ws;
  float* p    = (float*)ws;
  float* colC = (float*)(ws + 256);
  size_t off = 256 + (size_t)O * sizeof(float);
  off = (off + 255) & ~(size_t)255;
  float* rowC = (float*)(ws + off);
  off += (size_t)M * sizeof(float);
  off = (off + 255) & ~(size_t)255;
  int8_t* q1 = (int8_t*)(ws + off);
  off += (size_t)O * (size_t)K;
  int8_t* xq = (int8_t*)(ws + off);

  init_params_kernel<<<1, 1, 0, stream>>>(p);
  minmax_kernel<<<2048, 256, 0, stream>>>(x, xN, p + 0, p + 1);
  minmax_kernel<<<2048, 256, 0, stream>>>(W, wN, p + 2, p + 3);
  compute_params_kernel<<<1, 1, 0, stream>>>(p, bits, (float)K);
  quant_w_kernel<<<O, 256, 0, stream>>>(W, b, p, q1, colC, K);
  quant_x_kernel<<<M, 256, 0, stream>>>(x, p, xq, rowC, K);

  const int nwg = (M / 128) * (O / 128);
  gemm_i8_kernel<<<nwg, 256, 0, stream>>>(xq, q1, p, colC, rowC, (float*)d_out, M, O, K);
}

// Round 3
// 541.477 us; speedup vs baseline: 1.0603x; 1.0603x over previous
//
#include <hip/hip_runtime.h>
#include <hip/hip_bf16.h>
#include <cstdint>
#include <math.h>

typedef int v4i __attribute__((ext_vector_type(4)));

// ---------------- float atomic min/max via int tricks ----------------
__device__ __forceinline__ void atomicMinF(float* addr, float v) {
  if (v >= 0.f) atomicMin((int*)addr, __float_as_int(v));
  else          atomicMax((unsigned int*)addr, __float_as_uint(v));
}
__device__ __forceinline__ void atomicMaxF(float* addr, float v) {
  if (v >= 0.f) atomicMax((int*)addr, __float_as_int(v));
  else          atomicMin((unsigned int*)addr, __float_as_uint(v));
}

// ---------------- init params block (ws poisoned 0xAA every call) ----------------
__global__ void init_params_kernel(float* p) {
  p[0] =  INFINITY;  // xmin
  p[1] = -INFINITY;  // xmax
  p[2] =  INFINITY;  // wmin
  p[3] = -INFINITY;  // wmax
}

// ---------------- global min/max: 4 independent chains, 64B/lane ----------------
__global__ __launch_bounds__(256) void minmax_kernel(const float* __restrict__ a, long long n,
                                                     float* mnp, float* mxp) {
  const float4* a4 = (const float4*)a;
  const long long n4 = n >> 2;
  const long long tid = (long long)blockIdx.x * blockDim.x + threadIdx.x;
  const long long stride = (long long)gridDim.x * blockDim.x * 4;
  float mn0 = INFINITY, mx0 = -INFINITY, mn1 = INFINITY, mx1 = -INFINITY;
  float mn2 = INFINITY, mx2 = -INFINITY, mn3 = INFINITY, mx3 = -INFINITY;
  if (blockIdx.x == 0 && threadIdx.x < (int)(n & 3)) {
    float v = a[n4 * 4 + threadIdx.x];
    mn0 = fminf(mn0, v); mx0 = fmaxf(mx0, v);
  }
  long long i = tid * 4;
  for (; i + 4 <= n4; i += stride) {
    float4 v0 = a4[i], v1 = a4[i + 1], v2 = a4[i + 2], v3 = a4[i + 3];
    mn0 = fminf(mn0, fminf(fminf(v0.x, v0.y), fminf(v0.z, v0.w)));
    mx0 = fmaxf(mx0, fmaxf(fmaxf(v0.x, v0.y), fmaxf(v0.z, v0.w)));
    mn1 = fminf(mn1, fminf(fminf(v1.x, v1.y), fminf(v1.z, v1.w)));
    mx1 = fmaxf(mx1, fmaxf(fmaxf(v1.x, v1.y), fmaxf(v1.z, v1.w)));
    mn2 = fminf(mn2, fminf(fminf(v2.x, v2.y), fminf(v2.z, v2.w)));
    mx2 = fmaxf(mx2, fmaxf(fmaxf(v2.x, v2.y), fmaxf(v2.z, v2.w)));
    mn3 = fminf(mn3, fminf(fminf(v3.x, v3.y), fminf(v3.z, v3.w)));
    mx3 = fmaxf(mx3, fmaxf(fmaxf(v3.x, v3.y), fmaxf(v3.z, v3.w)));
  }
  for (; i < n4; ++i) {
    float4 v = a4[i];
    mn0 = fminf(mn0, fminf(fminf(v.x, v.y), fminf(v.z, v.w)));
    mx0 = fmaxf(mx0, fmaxf(fmaxf(v.x, v.y), fmaxf(v.z, v.w)));
  }
  float mn = fminf(fminf(mn0, mn1), fminf(mn2, mn3));
  float mx = fmaxf(fmaxf(mx0, mx1), fmaxf(mx2, mx3));
  #pragma unroll
  for (int off = 32; off; off >>= 1) {
    mn = fminf(mn, __shfl_xor(mn, off));
    mx = fmaxf(mx, __shfl_xor(mx, off));
  }
  __shared__ float smn[4], smx[4];
  int wv = threadIdx.x >> 6;
  if ((threadIdx.x & 63) == 0) { smn[wv] = mn; smx[wv] = mx; }
  __syncthreads();
  if (threadIdx.x == 0) {
    mn = fminf(fminf(smn[0], smn[1]), fminf(smn[2], smn[3]));
    mx = fmaxf(fmaxf(smx[0], smx[1]), fmaxf(smx[2], smx[3]));
    atomicMinF(mnp, mn);
    atomicMaxF(mxp, mx);
  }
}

// ---------------- scalar quant params (mirrors reference exactly) ----------------
__global__ void compute_params_kernel(float* p, const int* bits, float Kf) {
  float n   = (float)((1u << bits[0]) - 1u);
  float xmn = p[0], xmx = p[1], wmn = p[2], wmx = p[3];
  float S1 = (wmx - wmn) / n;
  float Z1 = rintf(n * wmn / (wmn - wmx));
  float S2 = (xmx - xmn) / n;
  float Z2 = rintf(n * xmn / (xmn - xmx));
  float s1s2 = S1 * S2;
  p[4]  = s1s2;
  p[5]  = 128.0f - Z2;                    // multiplies rowsum(q1)[o]
  p[6]  = 128.0f - Z1;                    // multiplies rowsum(xq)[i]
  p[7]  = (Z1 * Z2 - 16384.0f) * Kf;      // constant term
  p[8]  = S2;
  p[9]  = Z2;
  p[10] = wmn;
  p[11] = wmx - wmn;
  p[12] = n;
}

__device__ __forceinline__ unsigned qpack_w(float4 v, float wmn, float wrng, float n, int& sum) {
  int q0 = (int)rintf((v.x - wmn) / wrng * n);
  int q1 = (int)rintf((v.y - wmn) / wrng * n);
  int q2 = (int)rintf((v.z - wmn) / wrng * n);
  int q3 = (int)rintf((v.w - wmn) / wrng * n);
  sum += q0 + q1 + q2 + q3;
  return ((unsigned)((q0 - 128) & 255)) | ((unsigned)((q1 - 128) & 255) << 8)
       | ((unsigned)((q2 - 128) & 255) << 16) | ((unsigned)((q3 - 128) & 255) << 24);
}
__device__ __forceinline__ unsigned qpack_x(float4 v, float S2, float Z2, float n, int& sum) {
  int q0 = (int)fminf(fmaxf(rintf(v.x / S2 + Z2), 0.f), n);
  int q1 = (int)fminf(fmaxf(rintf(v.y / S2 + Z2), 0.f), n);
  int q2 = (int)fminf(fmaxf(rintf(v.z / S2 + Z2), 0.f), n);
  int q3 = (int)fminf(fmaxf(rintf(v.w / S2 + Z2), 0.f), n);
  sum += q0 + q1 + q2 + q3;
  return ((unsigned)((q0 - 128) & 255)) | ((unsigned)((q1 - 128) & 255) << 8)
       | ((unsigned)((q2 - 128) & 255) << 16) | ((unsigned)((q3 - 128) & 255) << 24);
}

// ---------------- quantize W row -> int8 (shifted -128), rowsum, col constant ----------------
__global__ __launch_bounds__(256) void quant_w_kernel(const float* __restrict__ W,
                                                      const float* __restrict__ bias,
                                                      const float* __restrict__ p,
                                                      int8_t* __restrict__ q1,
                                                      float* __restrict__ colC, int K) {
  const int o = blockIdx.x;
  const float wmn = p[10], wrng = p[11], n = p[12], s1s2 = p[4], cW = p[5], cC = p[7];
  const float4* Wr = (const float4*)(W + (size_t)o * K);
  unsigned int* qr = (unsigned int*)(q1 + (size_t)o * K);
  int sum = 0;
  const int K4 = K >> 2;
  int c = threadIdx.x;
  for (; c + 768 < K4; c += 1024) {
    float4 v0 = Wr[c], v1 = Wr[c + 256], v2 = Wr[c + 512], v3 = Wr[c + 768];
    qr[c]       = qpack_w(v0, wmn, wrng, n, sum);
    qr[c + 256] = qpack_w(v1, wmn, wrng, n, sum);
    qr[c + 512] = qpack_w(v2, wmn, wrng, n, sum);
    qr[c + 768] = qpack_w(v3, wmn, wrng, n, sum);
  }
  for (; c < K4; c += 256) qr[c] = qpack_w(Wr[c], wmn, wrng, n, sum);
  #pragma unroll
  for (int off = 32; off; off >>= 1) sum += __shfl_xor(sum, off);
  __shared__ int ps[4];
  if ((threadIdx.x & 63) == 0) ps[threadIdx.x >> 6] = sum;
  __syncthreads();
  if (threadIdx.x == 0) {
    float tot = (float)(ps[0] + ps[1] + ps[2] + ps[3]);
    colC[o] = cW * tot + rintf(bias[o] / s1s2) + cC;
  }
}

// ---------------- quantize x row -> int8 (shifted -128), rowsum, row constant ----------------
__global__ __launch_bounds__(256) void quant_x_kernel(const float* __restrict__ x,
                                                      const float* __restrict__ p,
                                                      int8_t* __restrict__ xq,
                                                      float* __restrict__ rowC, int K) {
  const int i = blockIdx.x;
  const float S2 = p[8], Z2 = p[9], n = p[12], cX = p[6];
  const float4* xr = (const float4*)(x + (size_t)i * K);
  unsigned int* qr = (unsigned int*)(xq + (size_t)i * K);
  int sum = 0;
  const int K4 = K >> 2;
  int c = threadIdx.x;
  for (; c + 768 < K4; c += 1024) {
    float4 v0 = xr[c], v1 = xr[c + 256], v2 = xr[c + 512], v3 = xr[c + 768];
    qr[c]       = qpack_x(v0, S2, Z2, n, sum);
    qr[c + 256] = qpack_x(v1, S2, Z2, n, sum);
    qr[c + 512] = qpack_x(v2, S2, Z2, n, sum);
    qr[c + 768] = qpack_x(v3, S2, Z2, n, sum);
  }
  for (; c < K4; c += 256) qr[c] = qpack_x(xr[c], S2, Z2, n, sum);
  #pragma unroll
  for (int off = 32; off; off >>= 1) sum += __shfl_xor(sum, off);
  __shared__ int ps[4];
  if ((threadIdx.x & 63) == 0) ps[threadIdx.x >> 6] = sum;
  __syncthreads();
  if (threadIdx.x == 0) {
    float tot = (float)(ps[0] + ps[1] + ps[2] + ps[3]);
    rowC[i] = cX * tot;
  }
}

// ---------------- async global->LDS 16B helper ----------------
__device__ __forceinline__ void gload_lds16(const void* g, void* l) {
  __builtin_amdgcn_global_load_lds((const __attribute__((address_space(1))) void*)g,
                                   (__attribute__((address_space(3))) void*)l, 16, 0, 0);
}

// ---------------- int8 MFMA GEMM, 256x256 tile, 8 waves, 4-phase schedule ----------------
// BM=BN=256, BK=64 bytes. 512 thr = 8 waves (2Mx4N), wave tile 128x64 = 8x4 frags 16x16x64.
// LDS: 2 dbuf x (16KB A + 16KB B) = 64KB. Raw s_barrier only (no vmcnt drain except the
// single counted point per K-tile). Swizzle: phys seg = global seg ^ ((row>>1)&3) ->
// conflict-free b128 reads (8-lane groups cover all 8 16B spans distinctly).
__global__ __launch_bounds__(512, 2) void gemm_i8_kernel(const int8_t* __restrict__ xq,
                                                         const int8_t* __restrict__ q1,
                                                         const float* __restrict__ p,
                                                         const float* __restrict__ colC,
                                                         const float* __restrict__ rowC,
                                                         float* __restrict__ out,
                                                         int M, int N, int K) {
  __shared__ int8_t As[2][256 * 64];
  __shared__ int8_t Bs[2][256 * 64];

  const int tid  = threadIdx.x;
  const int lane = tid & 63;
  const int wv   = tid >> 6;       // 0..7
  const int wr   = wv >> 2;        // 0..1  (M half)
  const int wc   = wv & 3;         // 0..3  (N quarter)
  const int r15  = lane & 15;
  const int kg   = lane >> 4;

  // 2-D XCD chunking: each XCD owns nbm/8 contiguous bm-rows (A panels pinned in its L2).
  const int nbm = M >> 8, nbn = N >> 8, nwg = nbm * nbn;
  int bm, bn;
  if (((nwg & 7) == 0) && ((nbm & 7) == 0)) {
    const int xcd = blockIdx.x & 7;
    const int idx = blockIdx.x >> 3;
    const int c   = nbm >> 3;
    bm = xcd * c + (idx % c);
    bn = idx / c;
  } else {
    bm = blockIdx.x / nbn;
    bn = blockIdx.x % nbn;
  }

  v4i acc[8][4];
  #pragma unroll
  for (int m = 0; m < 8; ++m)
    #pragma unroll
    for (int n = 0; n < 4; ++n) { v4i z = {0, 0, 0, 0}; acc[m][n] = z; }

  const size_t Abase = (size_t)bm * 256 * K;
  const size_t Bbase = (size_t)bn * 256 * K;
  const int srow = tid >> 2;                            // 0..127 per issue
  const int sgo  = ((tid & 3) ^ ((srow >> 1) & 3)) * 16; // pre-swizzled source seg byte off
  const int swx  = (kg ^ ((r15 >> 1) & 3)) << 4;         // read-side swizzled seg byte off

  int aoff[8], boff[4];
  #pragma unroll
  for (int m = 0; m < 8; ++m) aoff[m] = (wr * 128 + m * 16 + r15) * 64 + swx;
  #pragma unroll
  for (int n = 0; n < 4; ++n) boff[n] = (wc * 64 + n * 16 + r15) * 64 + swx;

  auto stage = [&](int8_t* la, int8_t* lb, int kof) {
    #pragma unroll
    for (int ii = 0; ii < 2; ++ii)
      gload_lds16(xq + Abase + (size_t)(ii * 128 + srow) * K + kof + sgo,
                  la + ii * 8192 + tid * 16);
    #pragma unroll
    for (int ii = 0; ii < 2; ++ii)
      gload_lds16(q1 + Bbase + (size_t)(ii * 128 + srow) * K + kof + sgo,
                  lb + ii * 8192 + tid * 16);
  };

  // prologue: stage tile 0
  stage(As[0], Bs[0], 0);
  asm volatile("s_waitcnt vmcnt(0)" ::: "memory");
  __builtin_amdgcn_s_barrier();

  const int NT = K >> 6;
  for (int t = 0; t < NT; ++t) {
    const int8_t* la = As[t & 1];
    const int8_t* lb = Bs[t & 1];
    int8_t* lan = As[(t & 1) ^ 1];
    int8_t* lbn = Bs[(t & 1) ^ 1];
    v4i bfr[4];
    #pragma unroll
    for (int ph = 0; ph < 4; ++ph) {
      v4i a0 = *(const v4i*)(la + aoff[2 * ph]);
      v4i a1 = *(const v4i*)(la + aoff[2 * ph + 1]);
      if (ph == 0) {
        #pragma unroll
        for (int n = 0; n < 4; ++n) bfr[n] = *(const v4i*)(lb + boff[n]);
        if (t + 1 < NT) stage(lan, lbn, (t + 1) << 6);   // prefetch flies under 4 phases
      }
      __builtin_amdgcn_s_barrier();
      __builtin_amdgcn_s_setprio(1);
      #pragma unroll
      for (int n = 0; n < 4; ++n)
        acc[2 * ph][n] = __builtin_amdgcn_mfma_i32_16x16x64_i8(a0, bfr[n], acc[2 * ph][n], 0, 0, 0);
      #pragma unroll
      for (int n = 0; n < 4; ++n)
        acc[2 * ph + 1][n] = __builtin_amdgcn_mfma_i32_16x16x64_i8(a1, bfr[n], acc[2 * ph + 1][n], 0, 0, 0);
      __builtin_amdgcn_s_setprio(0);
      if (ph == 3) asm volatile("s_waitcnt vmcnt(0)" ::: "memory");  // next tile landed
      __builtin_amdgcn_s_barrier();
    }
  }

  // epilogue: out[i,o] = s1s2 * (dot + colC[o] + rowC[i])
  const float s1s2 = p[4];
  const int orow0 = bm * 256 + wr * 128;
  const int ocol0 = bn * 256 + wc * 64;
  #pragma unroll
  for (int n = 0; n < 4; ++n) {
    const int go = ocol0 + n * 16 + r15;
    const float cc = colC[go];
    #pragma unroll
    for (int m = 0; m < 8; ++m) {
      const int gib = orow0 + m * 16 + kg * 4;
      #pragma unroll
      for (int r = 0; r < 4; ++r) {
        const int gi = gib + r;
        out[(size_t)gi * N + go] = s1s2 * ((float)acc[m][n][r] + cc + rowC[gi]);
      }
    }
  }
}

// ---------------- host launch ----------------
extern "C" void kernel_launch(void* const* d_in, const int* in_sizes, int n_in,
                              void* d_out, int out_size, void* d_ws, size_t ws_size,
                              hipStream_t stream) {
  const float* x    = (const float*)d_in[0];
  const float* W    = (const float*)d_in[1];
  const float* b    = (const float*)d_in[2];
  const int*   bits = (const int*)d_in[3];

  const long long xN = in_sizes[0];
  const long long wN = in_sizes[1];
  const int O = in_sizes[2];
  const int K = (int)(wN / O);
  const int M = (int)(xN / K);

  char* ws = (char*)d_ws;
  float* p    = (float*)ws;
  float* colC = (float*)(ws + 256);
  size_t off = 256 + (size_t)O * sizeof(float);
  off = (off + 255) & ~(size_t)255;
  float* rowC = (float*)(ws + off);
  off += (size_t)M * sizeof(float);
  off = (off + 255) & ~(size_t)255;
  int8_t* q1 = (int8_t*)(ws + off);
  off += (size_t)O * (size_t)K;
  int8_t* xq = (int8_t*)(ws + off);

  init_params_kernel<<<1, 1, 0, stream>>>(p);
  minmax_kernel<<<2048, 256, 0, stream>>>(x, xN, p + 0, p + 1);
  minmax_kernel<<<2048, 256, 0, stream>>>(W, wN, p + 2, p + 3);
  compute_params_kernel<<<1, 1, 0, stream>>>(p, bits, (float)K);
  quant_w_kernel<<<O, 256, 0, stream>>>(W, b, p, q1, colC, K);
  quant_x_kernel<<<M, 256, 0, stream>>>(x, p, xq, rowC, K);

  const int nwg = (M / 256) * (O / 256);
  gemm_i8_kernel<<<nwg, 512, 0, stream>>>(xq, q1, p, colC, rowC, (float*)d_out, M, O, K);
}